// Round 9
// baseline (554.215 us; speedup 1.0000x reference)
//
#include <hip/hip_runtime.h>
#include <hip/hip_bf16.h>
#include <stdint.h>

// ---------------------------------------------------------------------------
// y = w4( s1 ),  s1 = (1-g1)*h1 + z1   (s0 == 1 exactly: tanh saturation)
// R8: T2 swizzle killed bank conflicts (22M->0), 137->114us. Occupancy 11%:
//   64KB LDS (BK=64 dbuf) caps 2 blocks/CU; per-step chain latency exposed.
// R9: BK=32 -> LDS 32KB -> 5 blocks/CU (launch_bounds(256,5)); counted
//   vmcnt(4) dbuf kept; swizzle adapted to 64B rows: chunk ^= (row>>1)&3
//   (bank period 128B = 2 rows; plain row&3 leaves 4-way among rows 4 apart);
//   T5 setprio around MFMA cluster (5 blocks/CU = real role diversity).
// ---------------------------------------------------------------------------

typedef unsigned short u16;
using f32x4  = __attribute__((ext_vector_type(4))) float;
using bf16x8 = __attribute__((ext_vector_type(8))) short;

#define BATCH 16384
#define NIN   256
#define NHID  1024
#define NOUT  256

#define BM 128
#define BN 128
#define BK 32    // K-chunk per pipeline step (64B rows in LDS)

__device__ __forceinline__ u16 f2bf(float f) {
  unsigned u = __builtin_bit_cast(unsigned, f);
  unsigned r = 0x7fffu + ((u >> 16) & 1u);
  return (u16)((u + r) >> 16);
}
__device__ __forceinline__ float bf2f(u16 h) {
  unsigned u = ((unsigned)h) << 16;
  return __builtin_bit_cast(float, u);
}
__device__ __forceinline__ float fast_tanh(float x) {
  float cx = fminf(fmaxf(x, -15.f), 15.f);
  float e  = __expf(2.f * cx);
  return (e - 1.f) / (e + 1.f);
}

__device__ __forceinline__ void gload_lds16(const u16* g, u16* l) {
  __builtin_amdgcn_global_load_lds(
      (__attribute__((address_space(1))) void*)(const_cast<u16*>(g)),
      (__attribute__((address_space(3))) void*)(l),
      16, 0, 0);
}

// Stage a 128x32 bf16 tile (8KB), swizzled: LDS granule (row, j) holds global
// chunk (row, j ^ ((row>>1)&3)). LDS dest linear (DMA constraint, rule #21).
__device__ __forceinline__ void stage32(const u16* g0, int ld, u16* lds) {
  int t = threadIdx.x;
#pragma unroll
  for (int iss = 0; iss < 2; ++iss) {
    int idx = t + iss * 256;          // granule 0..511
    int row = idx >> 2;               // 4 granules (64B) per row
    int j   = idx & 3;
    int c   = (j ^ ((row >> 1) & 3)) << 3;  // pre-swizzled source chunk
    gload_lds16(g0 + (size_t)row * ld + c, lds + (size_t)idx * 8);
  }
}

// One BK=32 step: 16 MFMA per wave (4x4 frags). Reads apply the same XOR:
// global chunk q of row r lives at slot q ^ ((row>>1)&3); wm/wn/i*16 are
// multiples of 16 so (row>>1)&3 == (r>>1)&3. Residual 2-way alias (r, r+8)
// is free (m136).
__device__ __forceinline__ void mfma32(const u16* As, const u16* Bs,
                                       int wm, int wn, int lane,
                                       f32x4 acc[4][4]) {
  int r  = lane & 15;
  int q  = lane >> 4;                       // k-chunk 0..3
  int cx = (q ^ ((r >> 1) & 3)) << 3;       // swizzled elem offset in row
  bf16x8 a[4], b[4];
#pragma unroll
  for (int i = 0; i < 4; ++i)
    a[i] = *(const bf16x8*)(As + (size_t)((wm + i * 16 + r) * BK + cx));
#pragma unroll
  for (int j = 0; j < 4; ++j)
    b[j] = *(const bf16x8*)(Bs + (size_t)((wn + j * 16 + r) * BK + cx));
  __builtin_amdgcn_s_setprio(1);
#pragma unroll
  for (int i = 0; i < 4; ++i)
#pragma unroll
    for (int j = 0; j < 4; ++j)
      acc[i][j] = __builtin_amdgcn_mfma_f32_16x16x32_bf16(a[i], b[j], acc[i][j], 0, 0, 0);
  __builtin_amdgcn_s_setprio(0);
}

// One pipeline step: issue next-tile stage (4 instr), wait CURRENT tile
// (vmcnt(4): next's 4 stay in flight), barrier, compute, drain, barrier.
__device__ __forceinline__ void pipe_step(const u16* At, int lda,
                                          const u16* Bt, int ldb,
                                          int t, int STEPS,
                                          u16* Ac, u16* Bc, u16* An, u16* Bn,
                                          int wm, int wn, int lane,
                                          f32x4 acc[4][4]) {
  if (t + 1 < STEPS) {
    stage32(At + (size_t)(t + 1) * BK, lda, An);
    stage32(Bt + (size_t)(t + 1) * BK, ldb, Bn);
    asm volatile("s_waitcnt vmcnt(4)" ::: "memory");
  } else {
    asm volatile("s_waitcnt vmcnt(0)" ::: "memory");
  }
  __builtin_amdgcn_s_barrier();
  mfma32(Ac, Bc, wm, wn, lane, acc);
  asm volatile("s_waitcnt lgkmcnt(0)" ::: "memory");
  __builtin_amdgcn_s_barrier();
}

// A: MxK row-major(lda), B: NxK row-major(ldb) -> acc += A@B.T (tile m0,n0).
// smem: As0 | Bs0 | As1 | Bs1, 4096 u16 (8KB) each = 32KB total.
template<int STEPS>
__device__ __forceinline__ void gemm_pipe(const u16* A, int lda,
                                          const u16* B, int ldb,
                                          int m0, int n0, u16* sm,
                                          int wm, int wn, int lane,
                                          f32x4 acc[4][4]) {
  const u16* At = A + (size_t)m0 * lda;
  const u16* Bt = B + (size_t)n0 * ldb;
  u16* As0 = sm;          u16* Bs0 = sm + 4096;
  u16* As1 = sm + 8192;   u16* Bs1 = sm + 12288;
  stage32(At, lda, As0);
  stage32(Bt, ldb, Bs0);
  static_assert(STEPS % 2 == 0, "even steps");
#pragma unroll
  for (int tt = 0; tt < STEPS / 2; ++tt) {
    pipe_step(At, lda, Bt, ldb, 2 * tt,     STEPS, As0, Bs0, As1, Bs1, wm, wn, lane, acc);
    pipe_step(At, lda, Bt, ldb, 2 * tt + 1, STEPS, As1, Bs1, As0, Bs0, wm, wn, lane, acc);
  }
}

__device__ __forceinline__ void zero_acc(f32x4 acc[4][4]) {
  f32x4 z = {0.f, 0.f, 0.f, 0.f};
#pragma unroll
  for (int i = 0; i < 4; ++i)
#pragma unroll
    for (int j = 0; j < 4; ++j) acc[i][j] = z;
}

// --------------------------- prep kernels ----------------------------------

__global__ void k_prep_x(const float* __restrict__ x, u16* __restrict__ xa) {
  int i = blockIdx.x * 256 + threadIdx.x;
  float4 v = ((const float4*)x)[i];
  ushort4 o;
  o.x = f2bf(fabsf(v.x) + 0.1f);
  o.y = f2bf(fabsf(v.y) + 0.1f);
  o.z = f2bf(fabsf(v.z) + 0.1f);
  o.w = f2bf(fabsf(v.w) + 0.1f);
  ((ushort4*)xa)[i] = o;
}

struct WCvt { const float* src[6]; u16* dst[6]; int n[6]; };
__global__ void k_cvt(WCvt a) {
  int k = blockIdx.y;
  int i = blockIdx.x * 256 + threadIdx.x;
  if (i * 4 < a.n[k]) {
    float4 v = ((const float4*)a.src[k])[i];
    ushort4 o;
    o.x = f2bf(v.x); o.y = f2bf(v.y); o.z = f2bf(v.z); o.w = f2bf(v.w);
    ((ushort4*)a.dst[k])[i] = o;
  }
}

// c[n] = sum_k W[n,k] + b[n]  (s0==1 collapse of s0@W.T)
struct WSum { const float* w[3]; const float* b[3]; float* c[3]; };
__global__ void k_wsum(WSum a) {
  int g = blockIdx.y, n = blockIdx.x;
  const float* row = a.w[g] + (size_t)n * NHID;
  float s = 0.f;
  for (int k = threadIdx.x; k < NHID; k += 256) s += row[k];
#pragma unroll
  for (int o = 32; o; o >>= 1) s += __shfl_down(s, o, 64);
  __shared__ float sm[4];
  if ((threadIdx.x & 63) == 0) sm[threadIdx.x >> 6] = s;
  __syncthreads();
  if (threadIdx.x == 0) a.c[g][n] = sm[0] + sm[1] + sm[2] + sm[3] + a.b[g][n];
}

// --------------------------- GEMM passes -----------------------------------

// r1 = tanh(xa @ ur.T + cr)
__global__ __launch_bounds__(256, 5) void k_pass_r(const u16* __restrict__ xa,
                                                   const u16* __restrict__ ur,
                                                   const float* __restrict__ cr,
                                                   u16* __restrict__ r1) {
  __shared__ __align__(16) u16 smem[16384];
  int m0 = blockIdx.y * BM, n0 = blockIdx.x * BN;
  int lane = threadIdx.x & 63, wave = threadIdx.x >> 6;
  int wm = (wave >> 1) * 64, wn = (wave & 1) * 64;
  f32x4 acc[4][4];
  zero_acc(acc);
  gemm_pipe<8>(xa, NIN, ur, NIN, m0, n0, smem, wm, wn, lane, acc);

  int crw = (lane >> 4) * 4, cc = lane & 15;
#pragma unroll
  for (int ni = 0; ni < 4; ++ni) {
    int col = n0 + wn + ni * 16 + cc;
    float bias = cr[col];
#pragma unroll
    for (int mi = 0; mi < 4; ++mi)
#pragma unroll
      for (int r = 0; r < 4; ++r) {
        int row = m0 + wm + mi * 16 + crw + r;
        r1[(size_t)row * NHID + col] = f2bf(fast_tanh(acc[mi][ni][r] + bias));
      }
  }
}

// Fused: pg=1-tanh(xa@ug+cg), pz=tanh(xa@uz+cz) in regs (packed bf16);
//        h=tanh(xa@uh + r1@wh + bh);  s1 = pg*h + pz.
__global__ __launch_bounds__(256, 5) void k_gates_h(
    const u16* __restrict__ xa,
    const u16* __restrict__ ug, const u16* __restrict__ uz,
    const u16* __restrict__ uh,
    const float* __restrict__ cg, const float* __restrict__ cz,
    const float* __restrict__ bh,
    const u16* __restrict__ r1, const u16* __restrict__ wh,
    u16* __restrict__ s1) {
  __shared__ __align__(16) u16 smem[16384];

  // XCD-chunked swizzle: XCD k owns m-panels [16k,16k+16), n fastest ->
  // r1 panel (256KB) stays L2-resident across its 8 n-blocks.
  int wg  = blockIdx.x;
  int xcd = wg & 7;
  int idx = wg >> 3;
  int mb  = xcd * 16 + (idx >> 3);
  int nb  = idx & 7;
  int m0 = mb * BM, n0 = nb * BN;

  int lane = threadIdx.x & 63, wave = threadIdx.x >> 6;
  int wm = (wave >> 1) * 64, wn = (wave & 1) * 64;
  int crw = (lane >> 4) * 4, cc = lane & 15;

  f32x4 acc[4][4];
  unsigned pg[4][4][2], pz[4][4][2];   // packed bf16 pairs, static idx only

  // ---- gate g ----
  zero_acc(acc);
  gemm_pipe<8>(xa, NIN, ug, NIN, m0, n0, smem, wm, wn, lane, acc);
#pragma unroll
  for (int ni = 0; ni < 4; ++ni) {
    float cv = cg[n0 + wn + ni * 16 + cc];
#pragma unroll
    for (int mi = 0; mi < 4; ++mi) {
      float v0 = 1.f - fast_tanh(acc[mi][ni][0] + cv);
      float v1 = 1.f - fast_tanh(acc[mi][ni][1] + cv);
      float v2 = 1.f - fast_tanh(acc[mi][ni][2] + cv);
      float v3 = 1.f - fast_tanh(acc[mi][ni][3] + cv);
      pg[mi][ni][0] = (unsigned)f2bf(v0) | ((unsigned)f2bf(v1) << 16);
      pg[mi][ni][1] = (unsigned)f2bf(v2) | ((unsigned)f2bf(v3) << 16);
    }
  }

  // ---- gate z ----
  zero_acc(acc);
  gemm_pipe<8>(xa, NIN, uz, NIN, m0, n0, smem, wm, wn, lane, acc);
#pragma unroll
  for (int ni = 0; ni < 4; ++ni) {
    float cv = cz[n0 + wn + ni * 16 + cc];
#pragma unroll
    for (int mi = 0; mi < 4; ++mi) {
      float v0 = fast_tanh(acc[mi][ni][0] + cv);
      float v1 = fast_tanh(acc[mi][ni][1] + cv);
      float v2 = fast_tanh(acc[mi][ni][2] + cv);
      float v3 = fast_tanh(acc[mi][ni][3] + cv);
      pz[mi][ni][0] = (unsigned)f2bf(v0) | ((unsigned)f2bf(v1) << 16);
      pz[mi][ni][1] = (unsigned)f2bf(v2) | ((unsigned)f2bf(v3) << 16);
    }
  }

  // ---- h ----
  zero_acc(acc);
  gemm_pipe<8>(xa, NIN, uh, NIN, m0, n0, smem, wm, wn, lane, acc);
  gemm_pipe<32>(r1, NHID, wh, NHID, m0, n0, smem, wm, wn, lane, acc);

#pragma unroll
  for (int ni = 0; ni < 4; ++ni) {
    int col = n0 + wn + ni * 16 + cc;
    float bias = bh[col];
#pragma unroll
    for (int mi = 0; mi < 4; ++mi)
#pragma unroll
      for (int r = 0; r < 4; ++r) {
        int row = m0 + wm + mi * 16 + crw + r;
        float h = fast_tanh(acc[mi][ni][r] + bias);
        unsigned pgw = pg[mi][ni][r >> 1];
        unsigned pzw = pz[mi][ni][r >> 1];
        u16 pgh = (r & 1) ? (u16)(pgw >> 16) : (u16)(pgw & 0xffff);
        u16 pzh = (r & 1) ? (u16)(pzw >> 16) : (u16)(pzw & 0xffff);
        float s = bf2f(pgh) * h + bf2f(pzh);
        s1[(size_t)row * NHID + col] = f2bf(s);
      }
  }
}

// y = s1 @ w4.T (fp32 out)
__global__ __launch_bounds__(256, 5) void k_pass_c(const u16* __restrict__ s1,
                                                   const u16* __restrict__ w4,
                                                   float* __restrict__ y) {
  __shared__ __align__(16) u16 smem[16384];
  int m0 = blockIdx.y * BM, n0 = blockIdx.x * BN;
  int lane = threadIdx.x & 63, wave = threadIdx.x >> 6;
  int wm = (wave >> 1) * 64, wn = (wave & 1) * 64;
  f32x4 acc[4][4];
  zero_acc(acc);
  gemm_pipe<32>(s1, NHID, w4, NHID, m0, n0, smem, wm, wn, lane, acc);

  int crw = (lane >> 4) * 4, cc = lane & 15;
#pragma unroll
  for (int ni = 0; ni < 4; ++ni) {
    int col = n0 + wn + ni * 16 + cc;
#pragma unroll
    for (int mi = 0; mi < 4; ++mi)
#pragma unroll
      for (int r = 0; r < 4; ++r) {
        int row = m0 + wm + mi * 16 + crw + r;
        y[(size_t)row * NOUT + col] = acc[mi][ni][r];
      }
  }
}

// --------------------------- host ------------------------------------------

extern "C" void kernel_launch(void* const* d_in, const int* in_sizes, int n_in,
                              void* d_out, int out_size, void* d_ws, size_t ws_size,
                              hipStream_t stream) {
  (void)in_sizes; (void)n_in; (void)out_size; (void)ws_size;

  const float* x    = (const float*)d_in[0];
  const float* ug1  = (const float*)d_in[3];
  const float* wg1w = (const float*)d_in[4];
  const float* wg1b = (const float*)d_in[5];
  const float* uz1  = (const float*)d_in[6];
  const float* wz1w = (const float*)d_in[7];
  const float* wz1b = (const float*)d_in[8];
  const float* ur1  = (const float*)d_in[9];
  const float* wr1w = (const float*)d_in[10];
  const float* wr1b = (const float*)d_in[11];
  const float* uh1  = (const float*)d_in[12];
  const float* wh1w = (const float*)d_in[13];
  const float* wh1b = (const float*)d_in[14];
  const float* w4   = (const float*)d_in[27];
  float* y = (float*)d_out;

  uint8_t* ws = (uint8_t*)d_ws;
  size_t off = 0;
  auto carve = [&](size_t bytes) -> void* {
    void* p = ws + off;
    off += (bytes + 255) & ~(size_t)255;
    return p;
  };
  u16* xa  = (u16*)carve((size_t)BATCH * NIN * 2);    //  8 MB
  u16* r1  = (u16*)carve((size_t)BATCH * NHID * 2);   // 32 MB
  u16* s1  = (u16*)carve((size_t)BATCH * NHID * 2);   // 32 MB
  u16* bug = (u16*)carve((size_t)NHID * NIN * 2);
  u16* buz = (u16*)carve((size_t)NHID * NIN * 2);
  u16* bur = (u16*)carve((size_t)NHID * NIN * 2);
  u16* buh = (u16*)carve((size_t)NHID * NIN * 2);
  u16* bwh = (u16*)carve((size_t)NHID * NHID * 2);
  u16* bw4 = (u16*)carve((size_t)NOUT * NHID * 2);
  float* cg = (float*)carve(NHID * 4);
  float* cz = (float*)carve(NHID * 4);
  float* cr = (float*)carve(NHID * 4);

  k_prep_x<<<(BATCH * NIN) / (256 * 4), 256, 0, stream>>>(x, xa);

  WCvt wc;
  wc.src[0] = ug1;  wc.dst[0] = bug; wc.n[0] = NHID * NIN;
  wc.src[1] = uz1;  wc.dst[1] = buz; wc.n[1] = NHID * NIN;
  wc.src[2] = ur1;  wc.dst[2] = bur; wc.n[2] = NHID * NIN;
  wc.src[3] = uh1;  wc.dst[3] = buh; wc.n[3] = NHID * NIN;
  wc.src[4] = wh1w; wc.dst[4] = bwh; wc.n[4] = NHID * NHID;
  wc.src[5] = w4;   wc.dst[5] = bw4; wc.n[5] = NOUT * NHID;
  k_cvt<<<dim3(1024, 6), 256, 0, stream>>>(wc);

  WSum wsm;
  wsm.w[0] = wg1w; wsm.b[0] = wg1b; wsm.c[0] = cg;
  wsm.w[1] = wz1w; wsm.b[1] = wz1b; wsm.c[1] = cz;
  wsm.w[2] = wr1w; wsm.b[2] = wr1b; wsm.c[2] = cr;
  k_wsum<<<dim3(1024, 3), 256, 0, stream>>>(wsm);

  k_pass_r<<<dim3(NHID / BN, BATCH / BM), 256, 0, stream>>>(xa, bur, cr, r1);

  k_gates_h<<<(NHID / BN) * (BATCH / BM), 256, 0, stream>>>(
      xa, bug, buz, buh, cg, cz, wh1b, r1, bwh, s1);

  k_pass_c<<<dim3(NOUT / BN, BATCH / BM), 256, 0, stream>>>(s1, bw4, y);
}

// Round 10
// 183.498 us; speedup vs baseline: 3.0203x; 3.0203x over previous
//
#include <hip/hip_runtime.h>
#include <hip/hip_bf16.h>
#include <stdint.h>

// ---------------------------------------------------------------------------
// y = w4( s1 ),  s1 = (1-g1)*h1 + z1   (s0 == 1 exactly: tanh saturation)
// R9 FAILED: __launch_bounds__(256,5) capped ~102 VGPR < 168 needed ->
//   compiler spilled acc+pg+pz to scratch (VGPR 48, WRITE 1GB, 446us).
// R10: identical structure, launch_bounds(256,3) on k_gates_h (170 VGPR cap,
//   no spill, 3 blocks/CU vs R8's 2); (256,4) on pass_r/pass_c (~110 VGPR).
//   Keeps: BK=32 dbuf, counted vmcnt(4), XOR swizzle (row>>1)&3 (conflicts=0),
//   setprio around MFMA, XCD-chunked block swizzle.
// ---------------------------------------------------------------------------

typedef unsigned short u16;
using f32x4  = __attribute__((ext_vector_type(4))) float;
using bf16x8 = __attribute__((ext_vector_type(8))) short;

#define BATCH 16384
#define NIN   256
#define NHID  1024
#define NOUT  256

#define BM 128
#define BN 128
#define BK 32    // K-chunk per pipeline step (64B rows in LDS)

__device__ __forceinline__ u16 f2bf(float f) {
  unsigned u = __builtin_bit_cast(unsigned, f);
  unsigned r = 0x7fffu + ((u >> 16) & 1u);
  return (u16)((u + r) >> 16);
}
__device__ __forceinline__ float bf2f(u16 h) {
  unsigned u = ((unsigned)h) << 16;
  return __builtin_bit_cast(float, u);
}
__device__ __forceinline__ float fast_tanh(float x) {
  float cx = fminf(fmaxf(x, -15.f), 15.f);
  float e  = __expf(2.f * cx);
  return (e - 1.f) / (e + 1.f);
}

__device__ __forceinline__ void gload_lds16(const u16* g, u16* l) {
  __builtin_amdgcn_global_load_lds(
      (__attribute__((address_space(1))) void*)(const_cast<u16*>(g)),
      (__attribute__((address_space(3))) void*)(l),
      16, 0, 0);
}

// Stage a 128x32 bf16 tile (8KB), swizzled: LDS granule (row, j) holds global
// chunk (row, j ^ ((row>>1)&3)). LDS dest linear (DMA constraint, rule #21).
__device__ __forceinline__ void stage32(const u16* g0, int ld, u16* lds) {
  int t = threadIdx.x;
#pragma unroll
  for (int iss = 0; iss < 2; ++iss) {
    int idx = t + iss * 256;          // granule 0..511
    int row = idx >> 2;               // 4 granules (64B) per row
    int j   = idx & 3;
    int c   = (j ^ ((row >> 1) & 3)) << 3;  // pre-swizzled source chunk
    gload_lds16(g0 + (size_t)row * ld + c, lds + (size_t)idx * 8);
  }
}

// One BK=32 step: 16 MFMA per wave (4x4 frags). Reads apply the same XOR:
// global chunk q of row r lives at slot q ^ ((row>>1)&3); wm/wn/i*16 are
// multiples of 16 so (row>>1)&3 == (r>>1)&3. Residual 2-way alias (r, r+8)
// is free (m136).
__device__ __forceinline__ void mfma32(const u16* As, const u16* Bs,
                                       int wm, int wn, int lane,
                                       f32x4 acc[4][4]) {
  int r  = lane & 15;
  int q  = lane >> 4;                       // k-chunk 0..3
  int cx = (q ^ ((r >> 1) & 3)) << 3;       // swizzled elem offset in row
  bf16x8 a[4], b[4];
#pragma unroll
  for (int i = 0; i < 4; ++i)
    a[i] = *(const bf16x8*)(As + (size_t)((wm + i * 16 + r) * BK + cx));
#pragma unroll
  for (int j = 0; j < 4; ++j)
    b[j] = *(const bf16x8*)(Bs + (size_t)((wn + j * 16 + r) * BK + cx));
  __builtin_amdgcn_s_setprio(1);
#pragma unroll
  for (int i = 0; i < 4; ++i)
#pragma unroll
    for (int j = 0; j < 4; ++j)
      acc[i][j] = __builtin_amdgcn_mfma_f32_16x16x32_bf16(a[i], b[j], acc[i][j], 0, 0, 0);
  __builtin_amdgcn_s_setprio(0);
}

// One pipeline step: issue next-tile stage (4 instr), wait CURRENT tile
// (vmcnt(4): next's 4 stay in flight), barrier, compute, drain, barrier.
__device__ __forceinline__ void pipe_step(const u16* At, int lda,
                                          const u16* Bt, int ldb,
                                          int t, int STEPS,
                                          u16* Ac, u16* Bc, u16* An, u16* Bn,
                                          int wm, int wn, int lane,
                                          f32x4 acc[4][4]) {
  if (t + 1 < STEPS) {
    stage32(At + (size_t)(t + 1) * BK, lda, An);
    stage32(Bt + (size_t)(t + 1) * BK, ldb, Bn);
    asm volatile("s_waitcnt vmcnt(4)" ::: "memory");
  } else {
    asm volatile("s_waitcnt vmcnt(0)" ::: "memory");
  }
  __builtin_amdgcn_s_barrier();
  mfma32(Ac, Bc, wm, wn, lane, acc);
  asm volatile("s_waitcnt lgkmcnt(0)" ::: "memory");
  __builtin_amdgcn_s_barrier();
}

// A: MxK row-major(lda), B: NxK row-major(ldb) -> acc += A@B.T (tile m0,n0).
// smem: As0 | Bs0 | As1 | Bs1, 4096 u16 (8KB) each = 32KB total.
template<int STEPS>
__device__ __forceinline__ void gemm_pipe(const u16* A, int lda,
                                          const u16* B, int ldb,
                                          int m0, int n0, u16* sm,
                                          int wm, int wn, int lane,
                                          f32x4 acc[4][4]) {
  const u16* At = A + (size_t)m0 * lda;
  const u16* Bt = B + (size_t)n0 * ldb;
  u16* As0 = sm;          u16* Bs0 = sm + 4096;
  u16* As1 = sm + 8192;   u16* Bs1 = sm + 12288;
  stage32(At, lda, As0);
  stage32(Bt, ldb, Bs0);
  static_assert(STEPS % 2 == 0, "even steps");
#pragma unroll
  for (int tt = 0; tt < STEPS / 2; ++tt) {
    pipe_step(At, lda, Bt, ldb, 2 * tt,     STEPS, As0, Bs0, As1, Bs1, wm, wn, lane, acc);
    pipe_step(At, lda, Bt, ldb, 2 * tt + 1, STEPS, As1, Bs1, As0, Bs0, wm, wn, lane, acc);
  }
}

__device__ __forceinline__ void zero_acc(f32x4 acc[4][4]) {
  f32x4 z = {0.f, 0.f, 0.f, 0.f};
#pragma unroll
  for (int i = 0; i < 4; ++i)
#pragma unroll
    for (int j = 0; j < 4; ++j) acc[i][j] = z;
}

// --------------------------- prep kernels ----------------------------------

__global__ void k_prep_x(const float* __restrict__ x, u16* __restrict__ xa) {
  int i = blockIdx.x * 256 + threadIdx.x;
  float4 v = ((const float4*)x)[i];
  ushort4 o;
  o.x = f2bf(fabsf(v.x) + 0.1f);
  o.y = f2bf(fabsf(v.y) + 0.1f);
  o.z = f2bf(fabsf(v.z) + 0.1f);
  o.w = f2bf(fabsf(v.w) + 0.1f);
  ((ushort4*)xa)[i] = o;
}

struct WCvt { const float* src[6]; u16* dst[6]; int n[6]; };
__global__ void k_cvt(WCvt a) {
  int k = blockIdx.y;
  int i = blockIdx.x * 256 + threadIdx.x;
  if (i * 4 < a.n[k]) {
    float4 v = ((const float4*)a.src[k])[i];
    ushort4 o;
    o.x = f2bf(v.x); o.y = f2bf(v.y); o.z = f2bf(v.z); o.w = f2bf(v.w);
    ((ushort4*)a.dst[k])[i] = o;
  }
}

// c[n] = sum_k W[n,k] + b[n]  (s0==1 collapse of s0@W.T)
struct WSum { const float* w[3]; const float* b[3]; float* c[3]; };
__global__ void k_wsum(WSum a) {
  int g = blockIdx.y, n = blockIdx.x;
  const float* row = a.w[g] + (size_t)n * NHID;
  float s = 0.f;
  for (int k = threadIdx.x; k < NHID; k += 256) s += row[k];
#pragma unroll
  for (int o = 32; o; o >>= 1) s += __shfl_down(s, o, 64);
  __shared__ float sm[4];
  if ((threadIdx.x & 63) == 0) sm[threadIdx.x >> 6] = s;
  __syncthreads();
  if (threadIdx.x == 0) a.c[g][n] = sm[0] + sm[1] + sm[2] + sm[3] + a.b[g][n];
}

// --------------------------- GEMM passes -----------------------------------

// r1 = tanh(xa @ ur.T + cr)
__global__ __launch_bounds__(256, 4) void k_pass_r(const u16* __restrict__ xa,
                                                   const u16* __restrict__ ur,
                                                   const float* __restrict__ cr,
                                                   u16* __restrict__ r1) {
  __shared__ __align__(16) u16 smem[16384];
  int m0 = blockIdx.y * BM, n0 = blockIdx.x * BN;
  int lane = threadIdx.x & 63, wave = threadIdx.x >> 6;
  int wm = (wave >> 1) * 64, wn = (wave & 1) * 64;
  f32x4 acc[4][4];
  zero_acc(acc);
  gemm_pipe<8>(xa, NIN, ur, NIN, m0, n0, smem, wm, wn, lane, acc);

  int crw = (lane >> 4) * 4, cc = lane & 15;
#pragma unroll
  for (int ni = 0; ni < 4; ++ni) {
    int col = n0 + wn + ni * 16 + cc;
    float bias = cr[col];
#pragma unroll
    for (int mi = 0; mi < 4; ++mi)
#pragma unroll
      for (int r = 0; r < 4; ++r) {
        int row = m0 + wm + mi * 16 + crw + r;
        r1[(size_t)row * NHID + col] = f2bf(fast_tanh(acc[mi][ni][r] + bias));
      }
  }
}

// Fused: pg=1-tanh(xa@ug+cg), pz=tanh(xa@uz+cz) in regs (packed bf16);
//        h=tanh(xa@uh + r1@wh + bh);  s1 = pg*h + pz.
__global__ __launch_bounds__(256, 3) void k_gates_h(
    const u16* __restrict__ xa,
    const u16* __restrict__ ug, const u16* __restrict__ uz,
    const u16* __restrict__ uh,
    const float* __restrict__ cg, const float* __restrict__ cz,
    const float* __restrict__ bh,
    const u16* __restrict__ r1, const u16* __restrict__ wh,
    u16* __restrict__ s1) {
  __shared__ __align__(16) u16 smem[16384];

  // XCD-chunked swizzle: XCD k owns m-panels [16k,16k+16), n fastest ->
  // r1 panel (256KB) stays L2-resident across its 8 n-blocks.
  int wg  = blockIdx.x;
  int xcd = wg & 7;
  int idx = wg >> 3;
  int mb  = xcd * 16 + (idx >> 3);
  int nb  = idx & 7;
  int m0 = mb * BM, n0 = nb * BN;

  int lane = threadIdx.x & 63, wave = threadIdx.x >> 6;
  int wm = (wave >> 1) * 64, wn = (wave & 1) * 64;
  int crw = (lane >> 4) * 4, cc = lane & 15;

  f32x4 acc[4][4];
  unsigned pg[4][4][2], pz[4][4][2];   // packed bf16 pairs, static idx only

  // ---- gate g ----
  zero_acc(acc);
  gemm_pipe<8>(xa, NIN, ug, NIN, m0, n0, smem, wm, wn, lane, acc);
#pragma unroll
  for (int ni = 0; ni < 4; ++ni) {
    float cv = cg[n0 + wn + ni * 16 + cc];
#pragma unroll
    for (int mi = 0; mi < 4; ++mi) {
      float v0 = 1.f - fast_tanh(acc[mi][ni][0] + cv);
      float v1 = 1.f - fast_tanh(acc[mi][ni][1] + cv);
      float v2 = 1.f - fast_tanh(acc[mi][ni][2] + cv);
      float v3 = 1.f - fast_tanh(acc[mi][ni][3] + cv);
      pg[mi][ni][0] = (unsigned)f2bf(v0) | ((unsigned)f2bf(v1) << 16);
      pg[mi][ni][1] = (unsigned)f2bf(v2) | ((unsigned)f2bf(v3) << 16);
    }
  }

  // ---- gate z ----
  zero_acc(acc);
  gemm_pipe<8>(xa, NIN, uz, NIN, m0, n0, smem, wm, wn, lane, acc);
#pragma unroll
  for (int ni = 0; ni < 4; ++ni) {
    float cv = cz[n0 + wn + ni * 16 + cc];
#pragma unroll
    for (int mi = 0; mi < 4; ++mi) {
      float v0 = fast_tanh(acc[mi][ni][0] + cv);
      float v1 = fast_tanh(acc[mi][ni][1] + cv);
      float v2 = fast_tanh(acc[mi][ni][2] + cv);
      float v3 = fast_tanh(acc[mi][ni][3] + cv);
      pz[mi][ni][0] = (unsigned)f2bf(v0) | ((unsigned)f2bf(v1) << 16);
      pz[mi][ni][1] = (unsigned)f2bf(v2) | ((unsigned)f2bf(v3) << 16);
    }
  }

  // ---- h ----
  zero_acc(acc);
  gemm_pipe<8>(xa, NIN, uh, NIN, m0, n0, smem, wm, wn, lane, acc);
  gemm_pipe<32>(r1, NHID, wh, NHID, m0, n0, smem, wm, wn, lane, acc);

#pragma unroll
  for (int ni = 0; ni < 4; ++ni) {
    int col = n0 + wn + ni * 16 + cc;
    float bias = bh[col];
#pragma unroll
    for (int mi = 0; mi < 4; ++mi)
#pragma unroll
      for (int r = 0; r < 4; ++r) {
        int row = m0 + wm + mi * 16 + crw + r;
        float h = fast_tanh(acc[mi][ni][r] + bias);
        unsigned pgw = pg[mi][ni][r >> 1];
        unsigned pzw = pz[mi][ni][r >> 1];
        u16 pgh = (r & 1) ? (u16)(pgw >> 16) : (u16)(pgw & 0xffff);
        u16 pzh = (r & 1) ? (u16)(pzw >> 16) : (u16)(pzw & 0xffff);
        float s = bf2f(pgh) * h + bf2f(pzh);
        s1[(size_t)row * NHID + col] = f2bf(s);
      }
  }
}

// y = s1 @ w4.T (fp32 out)
__global__ __launch_bounds__(256, 4) void k_pass_c(const u16* __restrict__ s1,
                                                   const u16* __restrict__ w4,
                                                   float* __restrict__ y) {
  __shared__ __align__(16) u16 smem[16384];
  int m0 = blockIdx.y * BM, n0 = blockIdx.x * BN;
  int lane = threadIdx.x & 63, wave = threadIdx.x >> 6;
  int wm = (wave >> 1) * 64, wn = (wave & 1) * 64;
  f32x4 acc[4][4];
  zero_acc(acc);
  gemm_pipe<32>(s1, NHID, w4, NHID, m0, n0, smem, wm, wn, lane, acc);

  int crw = (lane >> 4) * 4, cc = lane & 15;
#pragma unroll
  for (int ni = 0; ni < 4; ++ni) {
    int col = n0 + wn + ni * 16 + cc;
#pragma unroll
    for (int mi = 0; mi < 4; ++mi)
#pragma unroll
      for (int r = 0; r < 4; ++r) {
        int row = m0 + wm + mi * 16 + crw + r;
        y[(size_t)row * NOUT + col] = acc[mi][ni][r];
      }
  }
}

// --------------------------- host ------------------------------------------

extern "C" void kernel_launch(void* const* d_in, const int* in_sizes, int n_in,
                              void* d_out, int out_size, void* d_ws, size_t ws_size,
                              hipStream_t stream) {
  (void)in_sizes; (void)n_in; (void)out_size; (void)ws_size;

  const float* x    = (const float*)d_in[0];
  const float* ug1  = (const float*)d_in[3];
  const float* wg1w = (const float*)d_in[4];
  const float* wg1b = (const float*)d_in[5];
  const float* uz1  = (const float*)d_in[6];
  const float* wz1w = (const float*)d_in[7];
  const float* wz1b = (const float*)d_in[8];
  const float* ur1  = (const float*)d_in[9];
  const float* wr1w = (const float*)d_in[10];
  const float* wr1b = (const float*)d_in[11];
  const float* uh1  = (const float*)d_in[12];
  const float* wh1w = (const float*)d_in[13];
  const float* wh1b = (const float*)d_in[14];
  const float* w4   = (const float*)d_in[27];
  float* y = (float*)d_out;

  uint8_t* ws = (uint8_t*)d_ws;
  size_t off = 0;
  auto carve = [&](size_t bytes) -> void* {
    void* p = ws + off;
    off += (bytes + 255) & ~(size_t)255;
    return p;
  };
  u16* xa  = (u16*)carve((size_t)BATCH * NIN * 2);    //  8 MB
  u16* r1  = (u16*)carve((size_t)BATCH * NHID * 2);   // 32 MB
  u16* s1  = (u16*)carve((size_t)BATCH * NHID * 2);   // 32 MB
  u16* bug = (u16*)carve((size_t)NHID * NIN * 2);
  u16* buz = (u16*)carve((size_t)NHID * NIN * 2);
  u16* bur = (u16*)carve((size_t)NHID * NIN * 2);
  u16* buh = (u16*)carve((size_t)NHID * NIN * 2);
  u16* bwh = (u16*)carve((size_t)NHID * NHID * 2);
  u16* bw4 = (u16*)carve((size_t)NOUT * NHID * 2);
  float* cg = (float*)carve(NHID * 4);
  float* cz = (float*)carve(NHID * 4);
  float* cr = (float*)carve(NHID * 4);

  k_prep_x<<<(BATCH * NIN) / (256 * 4), 256, 0, stream>>>(x, xa);

  WCvt wc;
  wc.src[0] = ug1;  wc.dst[0] = bug; wc.n[0] = NHID * NIN;
  wc.src[1] = uz1;  wc.dst[1] = buz; wc.n[1] = NHID * NIN;
  wc.src[2] = ur1;  wc.dst[2] = bur; wc.n[2] = NHID * NIN;
  wc.src[3] = uh1;  wc.dst[3] = buh; wc.n[3] = NHID * NIN;
  wc.src[4] = wh1w; wc.dst[4] = bwh; wc.n[4] = NHID * NHID;
  wc.src[5] = w4;   wc.dst[5] = bw4; wc.n[5] = NOUT * NHID;
  k_cvt<<<dim3(1024, 6), 256, 0, stream>>>(wc);

  WSum wsm;
  wsm.w[0] = wg1w; wsm.b[0] = wg1b; wsm.c[0] = cg;
  wsm.w[1] = wz1w; wsm.b[1] = wz1b; wsm.c[1] = cz;
  wsm.w[2] = wr1w; wsm.b[2] = wr1b; wsm.c[2] = cr;
  k_wsum<<<dim3(1024, 3), 256, 0, stream>>>(wsm);

  k_pass_r<<<dim3(NHID / BN, BATCH / BM), 256, 0, stream>>>(xa, bur, cr, r1);

  k_gates_h<<<(NHID / BN) * (BATCH / BM), 256, 0, stream>>>(
      xa, bug, buz, buh, cg, cz, wh1b, r1, bwh, s1);

  k_pass_c<<<dim3(NOUT / BN, BATCH / BM), 256, 0, stream>>>(s1, bw4, y);
}

// Round 11
// 159.546 us; speedup vs baseline: 3.4737x; 1.1501x over previous
//
#include <hip/hip_runtime.h>
#include <hip/hip_bf16.h>
#include <stdint.h>

// ---------------------------------------------------------------------------
// y = w4( s1 ),  s1 = (1-g1)*h1 + z1   (s0 == 1 exactly: tanh saturation)
// R9/R10 FAILED: __launch_bounds__(256,N) on this compiler caps VGPR at
//   ~256/N (N=3 -> 84, N=5 -> 48), NOT 512/N -> forced spill (WRITE 160MB-1GB).
// R11: no min-waves arg anywhere (R8's unbounded build: 168 VGPR, 0 spill).
//   + 2-deep prefetch / 3-buffer rotation at BK=32 (48KB LDS -> 3 blocks/CU;
//   VGPR 168 -> 12 waves/CU, limits agree). Counted vmcnt(8)/(4)/(0).
//   Keeps: XOR swizzle (row>>1)&3 (conflicts=0), setprio, XCD block swizzle.
// ---------------------------------------------------------------------------

typedef unsigned short u16;
using f32x4  = __attribute__((ext_vector_type(4))) float;
using bf16x8 = __attribute__((ext_vector_type(8))) short;

#define BATCH 16384
#define NIN   256
#define NHID  1024
#define NOUT  256

#define BM 128
#define BN 128
#define BK 32    // K-chunk per pipeline step (64B rows in LDS)

__device__ __forceinline__ u16 f2bf(float f) {
  unsigned u = __builtin_bit_cast(unsigned, f);
  unsigned r = 0x7fffu + ((u >> 16) & 1u);
  return (u16)((u + r) >> 16);
}
__device__ __forceinline__ float bf2f(u16 h) {
  unsigned u = ((unsigned)h) << 16;
  return __builtin_bit_cast(float, u);
}
__device__ __forceinline__ float fast_tanh(float x) {
  float cx = fminf(fmaxf(x, -15.f), 15.f);
  float e  = __expf(2.f * cx);
  return (e - 1.f) / (e + 1.f);
}

__device__ __forceinline__ void gload_lds16(const u16* g, u16* l) {
  __builtin_amdgcn_global_load_lds(
      (__attribute__((address_space(1))) void*)(const_cast<u16*>(g)),
      (__attribute__((address_space(3))) void*)(l),
      16, 0, 0);
}

// Stage a 128x32 bf16 tile (8KB), swizzled: LDS granule (row, j) holds global
// chunk (row, j ^ ((row>>1)&3)). LDS dest linear (DMA constraint, rule #21).
__device__ __forceinline__ void stage32(const u16* g0, int ld, u16* lds) {
  int t = threadIdx.x;
#pragma unroll
  for (int iss = 0; iss < 2; ++iss) {
    int idx = t + iss * 256;          // granule 0..511
    int row = idx >> 2;               // 4 granules (64B) per row
    int j   = idx & 3;
    int c   = (j ^ ((row >> 1) & 3)) << 3;  // pre-swizzled source chunk
    gload_lds16(g0 + (size_t)row * ld + c, lds + (size_t)idx * 8);
  }
}

// One BK=32 step: 16 MFMA per wave (4x4 frags). Reads apply the same XOR:
// chunk q of row r lives at slot q ^ ((r>>1)&3) (wm/wn/i*16 are multiples of
// 16 so row parity == r parity). Residual 2-way alias (r, r+8) is free (m136).
__device__ __forceinline__ void mfma32(const u16* As, const u16* Bs,
                                       int wm, int wn, int lane,
                                       f32x4 acc[4][4]) {
  int r  = lane & 15;
  int q  = lane >> 4;                       // k-chunk 0..3
  int cx = (q ^ ((r >> 1) & 3)) << 3;       // swizzled elem offset in row
  bf16x8 a[4], b[4];
#pragma unroll
  for (int i = 0; i < 4; ++i)
    a[i] = *(const bf16x8*)(As + (size_t)((wm + i * 16 + r) * BK + cx));
#pragma unroll
  for (int j = 0; j < 4; ++j)
    b[j] = *(const bf16x8*)(Bs + (size_t)((wn + j * 16 + r) * BK + cx));
  __builtin_amdgcn_s_setprio(1);
#pragma unroll
  for (int i = 0; i < 4; ++i)
#pragma unroll
    for (int j = 0; j < 4; ++j)
      acc[i][j] = __builtin_amdgcn_mfma_f32_16x16x32_bf16(a[i], b[j], acc[i][j], 0, 0, 0);
  __builtin_amdgcn_s_setprio(0);
}

// 3-buffer, 2-deep prefetch pipeline. smem: 3 x (A 4096 + B 4096) u16 = 48KB.
// Steady state: tiles t+1, t+2 in flight (8 loads) -> vmcnt(8) waits tile t.
template<int STEPS>
__device__ __forceinline__ void gemm_pipe(const u16* A, int lda,
                                          const u16* B, int ldb,
                                          int m0, int n0, u16* sm,
                                          int wm, int wn, int lane,
                                          f32x4 acc[4][4]) {
  const u16* At = A + (size_t)m0 * lda;
  const u16* Bt = B + (size_t)n0 * ldb;
  stage32(At, lda, sm);
  stage32(Bt, ldb, sm + 4096);
  if (STEPS > 1) {
    stage32(At + BK, lda, sm + 8192);
    stage32(Bt + BK, ldb, sm + 12288);
  }
#pragma unroll
  for (int t = 0; t < STEPS; ++t) {
    if (t + 2 < STEPS) {
      u16* buf = sm + (size_t)((t + 2) % 3) * 8192;
      stage32(At + (size_t)(t + 2) * BK, lda, buf);
      stage32(Bt + (size_t)(t + 2) * BK, ldb, buf + 4096);
      asm volatile("s_waitcnt vmcnt(8)" ::: "memory");
    } else if (t + 1 < STEPS) {
      asm volatile("s_waitcnt vmcnt(4)" ::: "memory");
    } else {
      asm volatile("s_waitcnt vmcnt(0)" ::: "memory");
    }
    __builtin_amdgcn_s_barrier();
    u16* cur = sm + (size_t)(t % 3) * 8192;
    mfma32(cur, cur + 4096, wm, wn, lane, acc);
    asm volatile("s_waitcnt lgkmcnt(0)" ::: "memory");
    __builtin_amdgcn_s_barrier();
  }
}

__device__ __forceinline__ void zero_acc(f32x4 acc[4][4]) {
  f32x4 z = {0.f, 0.f, 0.f, 0.f};
#pragma unroll
  for (int i = 0; i < 4; ++i)
#pragma unroll
    for (int j = 0; j < 4; ++j) acc[i][j] = z;
}

// --------------------------- prep kernels ----------------------------------

__global__ void k_prep_x(const float* __restrict__ x, u16* __restrict__ xa) {
  int i = blockIdx.x * 256 + threadIdx.x;
  float4 v = ((const float4*)x)[i];
  ushort4 o;
  o.x = f2bf(fabsf(v.x) + 0.1f);
  o.y = f2bf(fabsf(v.y) + 0.1f);
  o.z = f2bf(fabsf(v.z) + 0.1f);
  o.w = f2bf(fabsf(v.w) + 0.1f);
  ((ushort4*)xa)[i] = o;
}

struct WCvt { const float* src[6]; u16* dst[6]; int n[6]; };
__global__ void k_cvt(WCvt a) {
  int k = blockIdx.y;
  int i = blockIdx.x * 256 + threadIdx.x;
  if (i * 4 < a.n[k]) {
    float4 v = ((const float4*)a.src[k])[i];
    ushort4 o;
    o.x = f2bf(v.x); o.y = f2bf(v.y); o.z = f2bf(v.z); o.w = f2bf(v.w);
    ((ushort4*)a.dst[k])[i] = o;
  }
}

// c[n] = sum_k W[n,k] + b[n]  (s0==1 collapse of s0@W.T)
struct WSum { const float* w[3]; const float* b[3]; float* c[3]; };
__global__ void k_wsum(WSum a) {
  int g = blockIdx.y, n = blockIdx.x;
  const float* row = a.w[g] + (size_t)n * NHID;
  float s = 0.f;
  for (int k = threadIdx.x; k < NHID; k += 256) s += row[k];
#pragma unroll
  for (int o = 32; o; o >>= 1) s += __shfl_down(s, o, 64);
  __shared__ float sm[4];
  if ((threadIdx.x & 63) == 0) sm[threadIdx.x >> 6] = s;
  __syncthreads();
  if (threadIdx.x == 0) a.c[g][n] = sm[0] + sm[1] + sm[2] + sm[3] + a.b[g][n];
}

// --------------------------- GEMM passes -----------------------------------

// r1 = tanh(xa @ ur.T + cr)
__global__ __launch_bounds__(256) void k_pass_r(const u16* __restrict__ xa,
                                                const u16* __restrict__ ur,
                                                const float* __restrict__ cr,
                                                u16* __restrict__ r1) {
  __shared__ __align__(16) u16 smem[24576];
  int m0 = blockIdx.y * BM, n0 = blockIdx.x * BN;
  int lane = threadIdx.x & 63, wave = threadIdx.x >> 6;
  int wm = (wave >> 1) * 64, wn = (wave & 1) * 64;
  f32x4 acc[4][4];
  zero_acc(acc);
  gemm_pipe<8>(xa, NIN, ur, NIN, m0, n0, smem, wm, wn, lane, acc);

  int crw = (lane >> 4) * 4, cc = lane & 15;
#pragma unroll
  for (int ni = 0; ni < 4; ++ni) {
    int col = n0 + wn + ni * 16 + cc;
    float bias = cr[col];
#pragma unroll
    for (int mi = 0; mi < 4; ++mi)
#pragma unroll
      for (int r = 0; r < 4; ++r) {
        int row = m0 + wm + mi * 16 + crw + r;
        r1[(size_t)row * NHID + col] = f2bf(fast_tanh(acc[mi][ni][r] + bias));
      }
  }
}

// Fused: pg=1-tanh(xa@ug+cg), pz=tanh(xa@uz+cz) in regs (packed bf16);
//        h=tanh(xa@uh + r1@wh + bh);  s1 = pg*h + pz.
__global__ __launch_bounds__(256) void k_gates_h(
    const u16* __restrict__ xa,
    const u16* __restrict__ ug, const u16* __restrict__ uz,
    const u16* __restrict__ uh,
    const float* __restrict__ cg, const float* __restrict__ cz,
    const float* __restrict__ bh,
    const u16* __restrict__ r1, const u16* __restrict__ wh,
    u16* __restrict__ s1) {
  __shared__ __align__(16) u16 smem[24576];

  // XCD-chunked swizzle: XCD k owns m-panels [16k,16k+16), n fastest ->
  // r1 panel (256KB) stays L2-resident across its 8 n-blocks.
  int wg  = blockIdx.x;
  int xcd = wg & 7;
  int idx = wg >> 3;
  int mb  = xcd * 16 + (idx >> 3);
  int nb  = idx & 7;
  int m0 = mb * BM, n0 = nb * BN;

  int lane = threadIdx.x & 63, wave = threadIdx.x >> 6;
  int wm = (wave >> 1) * 64, wn = (wave & 1) * 64;
  int crw = (lane >> 4) * 4, cc = lane & 15;

  f32x4 acc[4][4];
  unsigned pg[4][4][2], pz[4][4][2];   // packed bf16 pairs, static idx only

  // ---- gate g ----
  zero_acc(acc);
  gemm_pipe<8>(xa, NIN, ug, NIN, m0, n0, smem, wm, wn, lane, acc);
#pragma unroll
  for (int ni = 0; ni < 4; ++ni) {
    float cv = cg[n0 + wn + ni * 16 + cc];
#pragma unroll
    for (int mi = 0; mi < 4; ++mi) {
      float v0 = 1.f - fast_tanh(acc[mi][ni][0] + cv);
      float v1 = 1.f - fast_tanh(acc[mi][ni][1] + cv);
      float v2 = 1.f - fast_tanh(acc[mi][ni][2] + cv);
      float v3 = 1.f - fast_tanh(acc[mi][ni][3] + cv);
      pg[mi][ni][0] = (unsigned)f2bf(v0) | ((unsigned)f2bf(v1) << 16);
      pg[mi][ni][1] = (unsigned)f2bf(v2) | ((unsigned)f2bf(v3) << 16);
    }
  }

  // ---- gate z ----
  zero_acc(acc);
  gemm_pipe<8>(xa, NIN, uz, NIN, m0, n0, smem, wm, wn, lane, acc);
#pragma unroll
  for (int ni = 0; ni < 4; ++ni) {
    float cv = cz[n0 + wn + ni * 16 + cc];
#pragma unroll
    for (int mi = 0; mi < 4; ++mi) {
      float v0 = fast_tanh(acc[mi][ni][0] + cv);
      float v1 = fast_tanh(acc[mi][ni][1] + cv);
      float v2 = fast_tanh(acc[mi][ni][2] + cv);
      float v3 = fast_tanh(acc[mi][ni][3] + cv);
      pz[mi][ni][0] = (unsigned)f2bf(v0) | ((unsigned)f2bf(v1) << 16);
      pz[mi][ni][1] = (unsigned)f2bf(v2) | ((unsigned)f2bf(v3) << 16);
    }
  }

  // ---- h ----
  zero_acc(acc);
  gemm_pipe<8>(xa, NIN, uh, NIN, m0, n0, smem, wm, wn, lane, acc);
  gemm_pipe<32>(r1, NHID, wh, NHID, m0, n0, smem, wm, wn, lane, acc);

#pragma unroll
  for (int ni = 0; ni < 4; ++ni) {
    int col = n0 + wn + ni * 16 + cc;
    float bias = bh[col];
#pragma unroll
    for (int mi = 0; mi < 4; ++mi)
#pragma unroll
      for (int r = 0; r < 4; ++r) {
        int row = m0 + wm + mi * 16 + crw + r;
        float h = fast_tanh(acc[mi][ni][r] + bias);
        unsigned pgw = pg[mi][ni][r >> 1];
        unsigned pzw = pz[mi][ni][r >> 1];
        u16 pgh = (r & 1) ? (u16)(pgw >> 16) : (u16)(pgw & 0xffff);
        u16 pzh = (r & 1) ? (u16)(pzw >> 16) : (u16)(pzw & 0xffff);
        float s = bf2f(pgh) * h + bf2f(pzh);
        s1[(size_t)row * NHID + col] = f2bf(s);
      }
  }
}

// y = s1 @ w4.T (fp32 out)
__global__ __launch_bounds__(256) void k_pass_c(const u16* __restrict__ s1,
                                                const u16* __restrict__ w4,
                                                float* __restrict__ y) {
  __shared__ __align__(16) u16 smem[24576];
  int m0 = blockIdx.y * BM, n0 = blockIdx.x * BN;
  int lane = threadIdx.x & 63, wave = threadIdx.x >> 6;
  int wm = (wave >> 1) * 64, wn = (wave & 1) * 64;
  f32x4 acc[4][4];
  zero_acc(acc);
  gemm_pipe<32>(s1, NHID, w4, NHID, m0, n0, smem, wm, wn, lane, acc);

  int crw = (lane >> 4) * 4, cc = lane & 15;
#pragma unroll
  for (int ni = 0; ni < 4; ++ni) {
    int col = n0 + wn + ni * 16 + cc;
#pragma unroll
    for (int mi = 0; mi < 4; ++mi)
#pragma unroll
      for (int r = 0; r < 4; ++r) {
        int row = m0 + wm + mi * 16 + crw + r;
        y[(size_t)row * NOUT + col] = acc[mi][ni][r];
      }
  }
}

// --------------------------- host ------------------------------------------

extern "C" void kernel_launch(void* const* d_in, const int* in_sizes, int n_in,
                              void* d_out, int out_size, void* d_ws, size_t ws_size,
                              hipStream_t stream) {
  (void)in_sizes; (void)n_in; (void)out_size; (void)ws_size;

  const float* x    = (const float*)d_in[0];
  const float* ug1  = (const float*)d_in[3];
  const float* wg1w = (const float*)d_in[4];
  const float* wg1b = (const float*)d_in[5];
  const float* uz1  = (const float*)d_in[6];
  const float* wz1w = (const float*)d_in[7];
  const float* wz1b = (const float*)d_in[8];
  const float* ur1  = (const float*)d_in[9];
  const float* wr1w = (const float*)d_in[10];
  const float* wr1b = (const float*)d_in[11];
  const float* uh1  = (const float*)d_in[12];
  const float* wh1w = (const float*)d_in[13];
  const float* wh1b = (const float*)d_in[14];
  const float* w4   = (const float*)d_in[27];
  float* y = (float*)d_out;

  uint8_t* ws = (uint8_t*)d_ws;
  size_t off = 0;
  auto carve = [&](size_t bytes) -> void* {
    void* p = ws + off;
    off += (bytes + 255) & ~(size_t)255;
    return p;
  };
  u16* xa  = (u16*)carve((size_t)BATCH * NIN * 2);    //  8 MB
  u16* r1  = (u16*)carve((size_t)BATCH * NHID * 2);   // 32 MB
  u16* s1  = (u16*)carve((size_t)BATCH * NHID * 2);   // 32 MB
  u16* bug = (u16*)carve((size_t)NHID * NIN * 2);
  u16* buz = (u16*)carve((size_t)NHID * NIN * 2);
  u16* bur = (u16*)carve((size_t)NHID * NIN * 2);
  u16* buh = (u16*)carve((size_t)NHID * NIN * 2);
  u16* bwh = (u16*)carve((size_t)NHID * NHID * 2);
  u16* bw4 = (u16*)carve((size_t)NOUT * NHID * 2);
  float* cg = (float*)carve(NHID * 4);
  float* cz = (float*)carve(NHID * 4);
  float* cr = (float*)carve(NHID * 4);

  k_prep_x<<<(BATCH * NIN) / (256 * 4), 256, 0, stream>>>(x, xa);

  WCvt wc;
  wc.src[0] = ug1;  wc.dst[0] = bug; wc.n[0] = NHID * NIN;
  wc.src[1] = uz1;  wc.dst[1] = buz; wc.n[1] = NHID * NIN;
  wc.src[2] = ur1;  wc.dst[2] = bur; wc.n[2] = NHID * NIN;
  wc.src[3] = uh1;  wc.dst[3] = buh; wc.n[3] = NHID * NIN;
  wc.src[4] = wh1w; wc.dst[4] = bwh; wc.n[4] = NHID * NHID;
  wc.src[5] = w4;   wc.dst[5] = bw4; wc.n[5] = NOUT * NHID;
  k_cvt<<<dim3(1024, 6), 256, 0, stream>>>(wc);

  WSum wsm;
  wsm.w[0] = wg1w; wsm.b[0] = wg1b; wsm.c[0] = cg;
  wsm.w[1] = wz1w; wsm.b[1] = wz1b; wsm.c[1] = cz;
  wsm.w[2] = wr1w; wsm.b[2] = wr1b; wsm.c[2] = cr;
  k_wsum<<<dim3(1024, 3), 256, 0, stream>>>(wsm);

  k_pass_r<<<dim3(NHID / BN, BATCH / BM), 256, 0, stream>>>(xa, bur, cr, r1);

  k_gates_h<<<(NHID / BN) * (BATCH / BM), 256, 0, stream>>>(
      xa, bug, buz, buh, cg, cz, wh1b, r1, bwh, s1);

  k_pass_c<<<dim3(NOUT / BN, BATCH / BM), 256, 0, stream>>>(s1, bw4, y);
}